// Round 3
// baseline (268.189 us; speedup 1.0000x reference)
//
#include <hip/hip_runtime.h>

typedef __attribute__((ext_vector_type(8))) short short8;
typedef __attribute__((ext_vector_type(4))) float floatx4;

#define D_NODE 64
#define D_OUT  64
#define ITERS 4

static __device__ __forceinline__ unsigned short f2bf(float x) {
    unsigned int u = __float_as_uint(x);
    unsigned int r = u + 0x7FFFu + ((u >> 16) & 1u);
    return (unsigned short)(r >> 16);
}

static __device__ __forceinline__ short8 cvt2(floatx4 x, floatx4 y) {
    short8 a;
    a[0] = (short)f2bf(x[0]); a[1] = (short)f2bf(x[1]);
    a[2] = (short)f2bf(x[2]); a[3] = (short)f2bf(x[3]);
    a[4] = (short)f2bf(y[0]); a[5] = (short)f2bf(y[1]);
    a[6] = (short)f2bf(y[2]); a[7] = (short)f2bf(y[3]);
    return a;
}

static __device__ __forceinline__ short8 load_cvt(const float* __restrict__ p) {
    return cvt2(*(const floatx4*)p, *(const floatx4*)(p + 4));
}

// wpe: 8 frags of W[0:64,:]   (fi = kstep*4 + ct): elem(lane,j) = W[kstep*32+(lane>>4)*8+j][ct*16+(lane&15)]
// wpn: 16 frags (fi = kstep*8 + ct, ct 0..7) covering NC's 128 cols: recv block then send block
// gc : b + globals @ W[192:224]
__global__ void pack2_kernel(const float* __restrict__ W, const float* __restrict__ b,
                             const float* __restrict__ g,
                             unsigned short* __restrict__ wpe,
                             unsigned short* __restrict__ wpn,
                             float* __restrict__ gc) {
    int tid = blockIdx.x * 256 + threadIdx.x;
    if (tid < 512) {
        int lane = tid & 63;
        int ct = (tid >> 6) & 3;
        int kstep = tid >> 8;
        int kbase = kstep * 32 + (lane >> 4) * 8;
        int col = ct * 16 + (lane & 15);
        short8 sv;
#pragma unroll
        for (int j = 0; j < 8; ++j)
            sv[j] = (short)f2bf(W[(size_t)(kbase + j) * D_OUT + col]);
        *(short8*)(wpe + (size_t)tid * 8) = sv;
    } else if (tid < 512 + 1024) {
        int t = tid - 512;
        int lane = t & 63;
        int ct = (t >> 6) & 7;
        int kstep = t >> 9;
        int kk = kstep * 32 + (lane >> 4) * 8;
        int c = ct * 16 + (lane & 15);
        int wrow = (c < 64) ? 64 : 128;
        int wcol = c & 63;
        short8 sv;
#pragma unroll
        for (int j = 0; j < 8; ++j)
            sv[j] = (short)f2bf(W[(size_t)(wrow + kk + j) * D_OUT + wcol]);
        *(short8*)(wpn + (size_t)t * 8) = sv;
    } else if (tid < 512 + 1024 + 64) {
        int col = tid - 1536;
        float acc = b[col];
#pragma unroll
        for (int k = 0; k < 32; ++k)
            acc += g[k] * W[(size_t)(192 + k) * D_OUT + col];
        gc[col] = acc;
    }
}

// NC[i][0:64] = nodes[i]@W[64:128]; NC[i][64:128] = nodes[i]@W[128:192]
// Swapped operands: D col = node index, D rows = NC cols -> float4 stores.
__global__ __launch_bounds__(256) void node2_kernel(
    const float* __restrict__ nodes, const unsigned short* __restrict__ wpn,
    float* __restrict__ NC, int Nn) {
    const int lane = threadIdx.x & 63;
    const int wave = threadIdx.x >> 6;
    const int g = lane >> 4;
    int nbase = blockIdx.x * 64 + wave * 16;
    if (nbase >= Nn) return;

    int na = nbase + (lane & 15);
    bool valid = na < Nn;
    if (!valid) na = Nn - 1;
    const float* pn = nodes + (size_t)na * D_NODE + g * 8;
    short8 N0 = load_cvt(pn);
    short8 N1 = load_cvt(pn + 32);

#pragma unroll
    for (int ct = 0; ct < 8; ++ct) {
        short8 B0 = *(const short8*)(wpn + ((size_t)ct * 64 + lane) * 8);
        short8 B1 = *(const short8*)(wpn + ((size_t)(8 + ct) * 64 + lane) * 8);
        floatx4 acc = (floatx4){0.f, 0.f, 0.f, 0.f};
        acc = __builtin_amdgcn_mfma_f32_16x16x32_bf16(B0, N0, acc, 0, 0, 0);
        acc = __builtin_amdgcn_mfma_f32_16x16x32_bf16(B1, N1, acc, 0, 0, 0);
        if (valid)
            *(floatx4*)(NC + (size_t)na * 128 + ct * 16 + g * 4) = acc;
    }
}

__global__ __launch_bounds__(256) void edge3_kernel(
    const float* __restrict__ edges,
    const int* __restrict__ recv, const int* __restrict__ send,
    const unsigned short* __restrict__ wpe, const float* __restrict__ NC,
    const float* __restrict__ gc, float* __restrict__ out, int E) {

    const int lane = threadIdx.x & 63;
    const int wave = threadIdx.x >> 6;
    const int g = lane >> 4;
    const int e16 = lane & 15;
    const int koff = g * 8;

    short8 Bf[8];
#pragma unroll
    for (int fi = 0; fi < 8; ++fi)
        Bf[fi] = *(const short8*)(wpe + ((size_t)fi * 64 + lane) * 8);

    floatx4 gv[4];
#pragma unroll
    for (int ct = 0; ct < 4; ++ct)
        gv[ct] = *(const floatx4*)(gc + ct * 16 + g * 4);

    const int base = blockIdx.x * (ITERS * 64) + wave * 16;

    // Hoist ALL index loads: breaks the idx->gather dependency out of the loop.
    int er[ITERS], ri[ITERS], si[ITERS];
#pragma unroll
    for (int it = 0; it < ITERS; ++it) {
        int r = base + it * 64 + e16;
        er[it] = (r < E) ? r : (E - 1);
        ri[it] = recv[er[it]];
        si[it] = send[er[it]];
    }

    floatx4 eraw[2][4];
    {
        const float* pe = edges + (size_t)er[0] * D_NODE + koff;
        eraw[0][0] = *(const floatx4*)pe;
        eraw[0][1] = *(const floatx4*)(pe + 4);
        eraw[0][2] = *(const floatx4*)(pe + 32);
        eraw[0][3] = *(const floatx4*)(pe + 36);
    }

#pragma unroll
    for (int it = 0; it < ITERS; ++it) {
        // 1) Issue gathers for this iteration first (addresses already in regs).
        floatx4 gr[4], gs[4];
#pragma unroll
        for (int ct = 0; ct < 4; ++ct) {
            gr[ct] = *(const floatx4*)(NC + (size_t)ri[it] * 128 + ct * 16 + g * 4);
            gs[ct] = *(const floatx4*)(NC + (size_t)si[it] * 128 + 64 + ct * 16 + g * 4);
        }

        // 2) Prefetch next iteration's edge rows.
        if (it + 1 < ITERS) {
            const float* pe = edges + (size_t)er[it + 1] * D_NODE + koff;
            eraw[(it + 1) & 1][0] = *(const floatx4*)pe;
            eraw[(it + 1) & 1][1] = *(const floatx4*)(pe + 4);
            eraw[(it + 1) & 1][2] = *(const floatx4*)(pe + 32);
            eraw[(it + 1) & 1][3] = *(const floatx4*)(pe + 36);
        }

        // 3) Convert current edge rows to bf16 fragments.
        short8 A0 = cvt2(eraw[it & 1][0], eraw[it & 1][1]);
        short8 A1 = cvt2(eraw[it & 1][2], eraw[it & 1][3]);

        // 4) MFMA: D col = edge, D row = out col (W frag as A-operand).
        floatx4 acc[4];
#pragma unroll
        for (int ct = 0; ct < 4; ++ct) acc[ct] = gv[ct];
#pragma unroll
        for (int ct = 0; ct < 4; ++ct) {
            acc[ct] = __builtin_amdgcn_mfma_f32_16x16x32_bf16(Bf[ct], A0, acc[ct], 0, 0, 0);
            acc[ct] = __builtin_amdgcn_mfma_f32_16x16x32_bf16(Bf[4 + ct], A1, acc[ct], 0, 0, 0);
        }

        // 5) Add gathered node contributions (f32 exact).
#pragma unroll
        for (int ct = 0; ct < 4; ++ct) acc[ct] += gr[ct] + gs[ct];

        // 6) Coalesced float4 stores: lane owns 4 consecutive cols of one row.
        int row = base + it * 64 + e16;
        if (row < E) {
            float* po = out + (size_t)row * D_OUT + g * 4;
#pragma unroll
            for (int ct = 0; ct < 4; ++ct)
                *(floatx4*)(po + ct * 16) = acc[ct];
        }
    }
}

// ---------------- Fallback path (round-1 kernel) if ws too small ----------------

#define NKSTEP 6
#define NFRAG  (NKSTEP * 4)

__global__ void pack_kernel(const float* __restrict__ W, const float* __restrict__ b,
                            const float* __restrict__ g,
                            unsigned short* __restrict__ wp, float* __restrict__ gc) {
    int tid = blockIdx.x * 256 + threadIdx.x;
    if (tid < NFRAG * 64) {
        int lane = tid & 63;
        int ct = (tid >> 6) & 3;
        int kstep = tid >> 8;
        int kbase = kstep * 32 + (lane >> 4) * 8;
        int col = ct * 16 + (lane & 15);
        short8 sv;
#pragma unroll
        for (int j = 0; j < 8; ++j)
            sv[j] = (short)f2bf(W[(size_t)(kbase + j) * D_OUT + col]);
        *(short8*)(wp + (size_t)tid * 8) = sv;
    } else if (tid < NFRAG * 64 + 64) {
        int col = tid - NFRAG * 64;
        float acc = b[col];
#pragma unroll
        for (int k = 0; k < 32; ++k)
            acc += g[k] * W[(size_t)(192 + k) * D_OUT + col];
        gc[col] = acc;
    }
}

__global__ __launch_bounds__(256) void edge_kernel(
    const float* __restrict__ edges, const float* __restrict__ nodes,
    const int* __restrict__ recv, const int* __restrict__ send,
    const unsigned short* __restrict__ wp, const float* __restrict__ gc,
    float* __restrict__ out, int E) {

    const int lane = threadIdx.x & 63;
    const int wave = threadIdx.x >> 6;

    short8 Bf[NFRAG];
#pragma unroll
    for (int fi = 0; fi < NFRAG; ++fi)
        Bf[fi] = *(const short8*)(wp + ((size_t)fi * 64 + lane) * 8);

    const int colbase = lane & 15;
    float gv[4];
#pragma unroll
    for (int ct = 0; ct < 4; ++ct) gv[ct] = gc[ct * 16 + colbase];

    const int koff = (lane >> 4) * 8;

    for (int it = 0; it < ITERS; ++it) {
        int ebase = (blockIdx.x * ITERS + it) * 64 + wave * 16;
        if (ebase >= E) break;

        int ea = ebase + (lane & 15);
        if (ea >= E) ea = E - 1;
        int ri = recv[ea];
        int si = send[ea];

        const float* pe = edges + (size_t)ea * D_NODE + koff;
        const float* pr = nodes + (size_t)ri * D_NODE + koff;
        const float* ps = nodes + (size_t)si * D_NODE + koff;

        short8 A[NKSTEP];
        A[0] = load_cvt(pe);
        A[1] = load_cvt(pe + 32);
        A[2] = load_cvt(pr);
        A[3] = load_cvt(pr + 32);
        A[4] = load_cvt(ps);
        A[5] = load_cvt(ps + 32);

        floatx4 acc[4];
#pragma unroll
        for (int ct = 0; ct < 4; ++ct)
            acc[ct] = (floatx4){gv[ct], gv[ct], gv[ct], gv[ct]};

#pragma unroll
        for (int ks = 0; ks < NKSTEP; ++ks) {
#pragma unroll
            for (int ct = 0; ct < 4; ++ct)
                acc[ct] = __builtin_amdgcn_mfma_f32_16x16x32_bf16(
                    A[ks], Bf[ks * 4 + ct], acc[ct], 0, 0, 0);
        }

        int crow = ebase + (lane >> 4) * 4;
#pragma unroll
        for (int ct = 0; ct < 4; ++ct) {
#pragma unroll
            for (int r4 = 0; r4 < 4; ++r4) {
                int row = crow + r4;
                if (row < E)
                    out[(size_t)row * D_OUT + ct * 16 + colbase] = acc[ct][r4];
            }
        }
    }
}

extern "C" void kernel_launch(void* const* d_in, const int* in_sizes, int n_in,
                              void* d_out, int out_size, void* d_ws, size_t ws_size,
                              hipStream_t stream) {
    const float* edges = (const float*)d_in[0];
    const float* nodes = (const float*)d_in[1];
    const float* glob  = (const float*)d_in[2];
    const int*   recv  = (const int*)d_in[3];
    const int*   send  = (const int*)d_in[4];
    const float* W     = (const float*)d_in[5];
    const float* b     = (const float*)d_in[6];
    float* out = (float*)d_out;

    int E  = in_sizes[0] / D_NODE;
    int Nn = in_sizes[1] / D_NODE;

    size_t nc_bytes  = (size_t)Nn * 128 * 4;
    size_t wpe_bytes = 512 * 8 * 2;
    size_t wpn_bytes = 1024 * 8 * 2;
    size_t need = nc_bytes + wpe_bytes + wpn_bytes + 256;

    int nblk = (E + ITERS * 64 - 1) / (ITERS * 64);

    if (ws_size >= need) {
        float* NC = (float*)d_ws;
        unsigned short* wpe = (unsigned short*)((char*)d_ws + nc_bytes);
        unsigned short* wpn = (unsigned short*)((char*)d_ws + nc_bytes + wpe_bytes);
        float* gc = (float*)((char*)d_ws + nc_bytes + wpe_bytes + wpn_bytes);

        pack2_kernel<<<7, 256, 0, stream>>>(W, b, glob, wpe, wpn, gc);
        node2_kernel<<<(Nn + 63) / 64, 256, 0, stream>>>(nodes, wpn, NC, Nn);
        edge3_kernel<<<nblk, 256, 0, stream>>>(edges, recv, send, wpe, NC, gc, out, E);
    } else {
        unsigned short* wp = (unsigned short*)d_ws;
        float* gc = (float*)((char*)d_ws + NFRAG * 64 * 8 * 2);
        pack_kernel<<<7, 256, 0, stream>>>(W, b, glob, wp, gc);
        edge_kernel<<<nblk, 256, 0, stream>>>(edges, nodes, recv, send, wp, gc, out, E);
    }
}